// Round 9
// baseline (158.789 us; speedup 1.0000x reference)
//
#include <hip/hip_runtime.h>

// Problem constants (fixed by setup_inputs)
#define B_   8
#define C_   64
#define O_   64
#define H_   128
#define W_   128
#define HO_  128
#define WO_  128
#define K2_  9
#define MOFF 18          // 2*K*K offset channels
#define PLANE (H_*W_)    // 16384
#define KTOT 576         // C_*K2_

// Row-band geometry (R13): rows ho-2..ho+2, cols -2..129 (zero-padded).
// Two planes (kh = channel half), each [5][132] cells of 16B (8 bf16).
#define BROWS 5
#define BCOLS 132
#define PSTRIDE (BROWS*BCOLS*8)   // 5280 ushorts = 10,560 B per plane

typedef short bf16x8 __attribute__((ext_vector_type(8)));
typedef float f32x16 __attribute__((ext_vector_type(16)));
typedef float f32x2  __attribute__((ext_vector_type(2)));
typedef unsigned int u32x4 __attribute__((ext_vector_type(4)));

__device__ __forceinline__ unsigned short f2bf(float f) {
    // round-to-nearest-even fp32 -> bf16
    unsigned u = __float_as_uint(f);
    u += 0x7fff + ((u >> 16) & 1);
    return (unsigned short)(u >> 16);
}
__device__ __forceinline__ float bf2f(short v) {
    return __uint_as_float(((unsigned)(unsigned short)v) << 16);
}
// unpack u32 (2 bf16) -> 2 floats (1 inst each: shl / and)
__device__ __forceinline__ f32x2 unpk(unsigned w) {
    f32x2 r;
    r.x = __uint_as_float(w << 16);
    r.y = __uint_as_float(w & 0xffff0000u);
    return r;
}

// ---------------------------------------------------------------------------
// PREP (merged): blocks < 1024 do the NHWC transpose; blocks >= 1024 convert
// both weight tensors to bf16 TAP-MAJOR rows (R16 vectorized version).
// xt layout (chunk-major NHWC):
//   xt[((cc*B + b)*PLANE + y*W + px)*16 + cl] = bf16(x[((b*64+cc*16+cl)*H+y)*W+px])
// ---------------------------------------------------------------------------
__global__ __launch_bounds__(256) void prep_kernel(const float* __restrict__ x,
                                                   const float* __restrict__ w,
                                                   const float* __restrict__ w_off,
                                                   unsigned short* __restrict__ xt,
                                                   unsigned short* __restrict__ wbf) {
    __shared__ __align__(16) unsigned short T[64 * 132];  // stride 132: ushort4-aligned
    const int tid = threadIdx.x;
    if (blockIdx.x >= B_ * H_) {                // ---- weight conversion ----
        int i = (blockIdx.x - B_ * H_) * 256 + tid;   // 96*576 = 55296
        if (i < 96 * KTOT) {
            int o = i / KTOT, pos = i % KTOT;
            int cc = pos / 144, r = pos % 144, t = r / 16, cl = r % 16;
            int c = cc * 16 + cl;
            unsigned short v;
            if (o < O_)             v = f2bf(w[o * KTOT + c * 9 + t]);
            else if (o < O_ + MOFF) v = f2bf(w_off[(o - O_) * KTOT + c * 9 + t]);
            else                    v = 0;
            wbf[i] = v;
        }
        return;
    }
    // ---- NHWC transpose ----
    const int b = blockIdx.x & 7;
    const int y = blockIdx.x >> 3;
    const float4* src4 = (const float4*)(x + (size_t)b * C_ * PLANE + y * W_);
    for (int i = tid; i < 64 * 32; i += 256) {  // 2048 float4 cells, 8 iters
        int c = i >> 5, px4 = i & 31;
        float4 v = src4[c * (PLANE / 4) + px4];
        ushort4 t = { f2bf(v.x), f2bf(v.y), f2bf(v.z), f2bf(v.w) };
        *(ushort4*)&T[c * 132 + px4 * 4] = t;
    }
    __syncthreads();
    for (int j = tid; j < 128 * 4; j += 256) {
        int cc = j >> 7, px = j & 127;
        unsigned short* dst = xt + ((size_t)(cc * B_ + b) * PLANE + y * W_ + px) * 16;
        ushort4 v0 = { T[(cc*16+ 0)*132+px], T[(cc*16+ 1)*132+px],
                       T[(cc*16+ 2)*132+px], T[(cc*16+ 3)*132+px] };
        ushort4 v1 = { T[(cc*16+ 4)*132+px], T[(cc*16+ 5)*132+px],
                       T[(cc*16+ 6)*132+px], T[(cc*16+ 7)*132+px] };
        ushort4 v2 = { T[(cc*16+ 8)*132+px], T[(cc*16+ 9)*132+px],
                       T[(cc*16+10)*132+px], T[(cc*16+11)*132+px] };
        ushort4 v3 = { T[(cc*16+12)*132+px], T[(cc*16+13)*132+px],
                       T[(cc*16+14)*132+px], T[(cc*16+15)*132+px] };
        *(ushort4*)(dst)      = v0;
        *(ushort4*)(dst + 4)  = v1;
        *(ushort4*)(dst + 8)  = v2;
        *(ushort4*)(dst + 12) = v3;
    }
}

// ---------------------------------------------------------------------------
// FUSED offset-conv + deformable-conv (R18 = R15 + forced 3-tap ILP groups).
// R17 post-mortem: implicit cur/nxt pipeline was re-serialized by the
// scheduler (VGPR stayed 64 = pressure clamp; dur 66->69). R18 makes the ILP
// structural: per cc-chunk, taps are processed in groups of 3 --
//   { 6 lo reads + coords + 12 corner ds_read_b128 issued together }
//   -> __builtin_amdgcn_sched_barrier(0)   (loads cannot be sunk past it)
//   -> { 3 blends + 6 MFMAs }
// One LDS round-trip (~120-200cy) amortizes over 3 taps instead of per-tap.
// Reg cost: 48 corners + ~25 coord/temps + 32 acc ~= 105 < 128 budget (256,4).
// KEY SIGNAL: VGPR_Count must rise to ~96-128; if it stays 64 the scheduler
// won this round too and 66us is the practical floor of this structure.
// Everything else identical to R15 (66.0us): band staging phase A, packed
// blend, per-cc coord recompute, slow path, epilogue.
// LDS = 21,120(band) + 9,216(lo) = 30,336 B.
// Tripwire: WRITE_SIZE > ~33MB = spill -> fall back to 2-tap groups.
// ---------------------------------------------------------------------------
__global__ __launch_bounds__(256, 4) void fused_kernel(const unsigned short* __restrict__ xt,
        const unsigned short* __restrict__ wobf, const float* __restrict__ b_off,
        const unsigned short* __restrict__ wbf, const float* __restrict__ bias,
        float* __restrict__ out) {
    __shared__ __align__(16) unsigned short band[2 * PSTRIDE];   // 21,120 B
    __shared__ float lo[MOFF * 128];                             // 9,216 B
    const int tid  = threadIdx.x;
    const int id   = blockIdx.x;                // 1024
    const int b    = id & 7;                    // batch-per-XCD heuristic
    const int ho   = id >> 3;
    const int wv   = tid >> 6;                  // wave 0..3
    const int lane = tid & 63;
    const int m    = lane & 31;
    const int kh   = lane >> 5;                 // channel half
    const int pxg  = (wv << 5) + m;             // owned output pixel

    // Coalesced band staging: position j=(r,c); thread loads 32B (16 ch) and
    // writes 16B to each plane. Consecutive threads read consecutive 32B.
    auto stage = [&](const unsigned short* xtc, int r0, int nrows) {
        const int npos = nrows * BCOLS;
        uint4 va[3], vb[3];
        #pragma unroll
        for (int it = 0; it < 3; ++it) {        // issue all loads first
            va[it] = (uint4){0, 0, 0, 0};
            vb[it] = (uint4){0, 0, 0, 0};
            int j = tid + it * 256;
            if (j < npos) {
                int r = j / BCOLS, c = j - r * BCOLS;
                int y = ho - 2 + r0 + r, x = c - 2;
                if (((unsigned)y < (unsigned)H_) && ((unsigned)x < (unsigned)W_)) {
                    const uint4* gp = (const uint4*)(xtc + (y * W_ + x) * 16);
                    va[it] = gp[0];
                    vb[it] = gp[1];
                }
            }
        }
        #pragma unroll
        for (int it = 0; it < 3; ++it) {
            int j = tid + it * 256;
            if (j < npos) {
                int r = j / BCOLS, c = j - r * BCOLS;
                int s = ((r0 + r) * BCOLS + c) * 8;
                *(uint4*)&band[s]           = va[it];
                *(uint4*)&band[PSTRIDE + s] = vb[it];
            }
        }
    };

    // ================= Phase A: offset conv (per-wave M=32, N=32) ==========
    f32x16 acc0 = {};
    for (int cc = 0; cc < 4; ++cc) {
        const unsigned short* xtc = xt + (size_t)(cc * B_ + b) * PLANE * 16;
        stage(xtc, 1, 3);                       // taps only touch rows 1..3
        __syncthreads();                        // band ready
        #pragma unroll
        for (int ks = 0; ks < 9; ++ks) {
            bf16x8 a = *(const bf16x8*)&wobf[m * KTOT + cc * 144 + ks * 16 + kh * 8];
            bf16x8 s = *(const bf16x8*)&band[kh * PSTRIDE +
                        ((1 + ks / 3) * BCOLS + pxg + ks % 3 + 1) * 8];
            acc0 = __builtin_amdgcn_mfma_f32_32x32x16_bf16(a, s, acc0, 0, 0, 0);
        }
        __syncthreads();                        // reads done before restage
    }
    // offsets -> lo[mo][px] (D col = pixel = lane m -> own px tile)
    #pragma unroll
    for (int r = 0; r < 16; ++r) {
        int mo = (r & 3) + ((r >> 2) << 3) + (kh << 2);
        if (mo < MOFF) lo[mo * 128 + pxg] = acc0[r] + b_off[mo];
    }
    __syncthreads();                            // lo ready

    // ================= Phase B: deformable conv (per-wave M=64, N=32) ======
    f32x16 acc[2] = {};
    for (int cc = 0; cc < 4; ++cc) {
        const unsigned short* xtc = xt + (size_t)(cc * B_ + b) * PLANE * 16;
        stage(xtc, 0, 5);                       // full 5-row band
        __syncthreads();                        // band ready
        #pragma unroll
        for (int g = 0; g < 3; ++g) {           // 3 taps per group
            // ---- coord + corner loads for taps 3g..3g+2, issued together ----
            float wyA[3], wxA[3];
            int   y0A[3], x0A[3], oobA[3];
            const unsigned short* bpA[3];
            #pragma unroll
            for (int i = 0; i < 3; ++i) {
                const int ks = g * 3 + i;
                float py  = (float)(ho - 1 + ks / 3) + lo[(2 * ks) * 128 + pxg];
                float pxc = (float)(pxg - 1 + ks % 3) + lo[(2 * ks + 1) * 128 + pxg];
                float fy = floorf(py), fx = floorf(pxc);
                wyA[i] = py - fy;  wxA[i] = pxc - fx;
                y0A[i] = (int)fy;  x0A[i] = (int)fx;
                int rb_ = y0A[i] - ho + 2, cb = x0A[i] + 2;
                oobA[i] = ((unsigned)rb_ > 3u) || ((unsigned)cb > 130u);
                int rbc = min(max(rb_, 0), 3), cbc = min(max(cb, 0), 130);
                bpA[i] = &band[kh * PSTRIDE + (rbc * BCOLS + cbc) * 8];
            }
            uint4 c00[3], c01[3], c10[3], c11[3];   // 48 VGPR, static idx
            #pragma unroll
            for (int i = 0; i < 3; ++i) {
                c00[i] = *(const uint4*)bpA[i];
                c01[i] = *(const uint4*)(bpA[i] + 8);
                c10[i] = *(const uint4*)(bpA[i] + BCOLS * 8);
                c11[i] = *(const uint4*)(bpA[i] + BCOLS * 8 + 8);
            }
            // fence: the 12 ds_reads above cannot be sunk below this point
            __builtin_amdgcn_sched_barrier(0);
            // ---- blend + MFMA for the 3 taps ----
            #pragma unroll
            for (int i = 0; i < 3; ++i) {
                const int ks = g * 3 + i;
                const f32x2 wx2 = { wxA[i], wxA[i] };
                const f32x2 wy2 = { wyA[i], wyA[i] };
                u32x4 vr;
                #pragma unroll
                for (int pq = 0; pq < 4; ++pq) {
                    unsigned w00 = (pq==0)?c00[i].x:(pq==1)?c00[i].y:(pq==2)?c00[i].z:c00[i].w;
                    unsigned w01 = (pq==0)?c01[i].x:(pq==1)?c01[i].y:(pq==2)?c01[i].z:c01[i].w;
                    unsigned w10 = (pq==0)?c10[i].x:(pq==1)?c10[i].y:(pq==2)?c10[i].z:c10[i].w;
                    unsigned w11 = (pq==0)?c11[i].x:(pq==1)?c11[i].y:(pq==2)?c11[i].z:c11[i].w;
                    f32x2 a2 = unpk(w00), b2 = unpk(w01);
                    f32x2 c2 = unpk(w10), d2 = unpk(w11);
                    f32x2 top = a2 + wx2 * (b2 - a2);     // v_pk ops on CDNA
                    f32x2 bot = c2 + wx2 * (d2 - c2);
                    f32x2 r2  = top + wy2 * (bot - top);
                    unsigned pk;
                    asm("v_cvt_pk_bf16_f32 %0, %1, %2" : "=v"(pk) : "v"(r2.x), "v"(r2.y));
                    vr[pq] = pk;
                }
                bf16x8 v = __builtin_bit_cast(bf16x8, vr);
                // rare slow path: offsets outside the band -> exact gather
                if (__builtin_expect(__any(oobA[i]), 0)) {
                    if (oobA[i]) {
                        float wy = wyA[i], wx = wxA[i];
                        float s8[8];
                        #pragma unroll
                        for (int j = 0; j < 8; ++j) s8[j] = 0.f;
                        #pragma unroll
                        for (int c2i = 0; c2i < 4; ++c2i) {
                            int yy = y0A[i] + (c2i >> 1);
                            int xx = x0A[i] + (c2i & 1);
                            bool valid = ((unsigned)yy < (unsigned)H_) && ((unsigned)xx < (unsigned)W_);
                            int yc = min(max(yy, 0), H_ - 1);
                            int xc = min(max(xx, 0), W_ - 1);
                            float wgt = ((c2i >> 1) ? wy : 1.f - wy) * ((c2i & 1) ? wx : 1.f - wx);
                            wgt = valid ? wgt : 0.f;
                            const unsigned short* rp = xtc + (yc * W_ + xc) * 16 + kh * 8;
                            bf16x8 u = *(const bf16x8*)rp;
                            #pragma unroll
                            for (int j = 0; j < 8; ++j) s8[j] += wgt * bf2f(u[j]);
                        }
                        #pragma unroll
                        for (int j = 0; j < 8; ++j) v[j] = (short)f2bf(s8[j]);
                    }
                }
                // MFMA: M=64 via two A-rows; A-fragments lazy (L2-hot wbf)
                bf16x8 a0 = *(const bf16x8*)&wbf[m * KTOT + cc * 144 + ks * 16 + kh * 8];
                bf16x8 a1 = *(const bf16x8*)&wbf[(32 + m) * KTOT + cc * 144 + ks * 16 + kh * 8];
                acc[0] = __builtin_amdgcn_mfma_f32_32x32x16_bf16(a0, v, acc[0], 0, 0, 0);
                acc[1] = __builtin_amdgcn_mfma_f32_32x32x16_bf16(a1, v, acc[1], 0, 0, 0);
            }
        }
        __syncthreads();                        // reads done before restage
    }

    // epilogue: D col = pixel (pxg), row = out channel (+32 for acc[1])
    {
        float* op = out + (size_t)b * O_ * PLANE + ho * WO_ + pxg;
        #pragma unroll
        for (int nt = 0; nt < 2; ++nt) {
            #pragma unroll
            for (int r = 0; r < 16; ++r) {
                int mo = (nt << 5) + (r & 3) + ((r >> 2) << 3) + (kh << 2);
                __builtin_nontemporal_store(acc[nt][r] + bias[mo], op + (size_t)mo * PLANE);
            }
        }
    }
}

// ---------------------------------------------------------------------------
extern "C" void kernel_launch(void* const* d_in, const int* in_sizes, int n_in,
                              void* d_out, int out_size, void* d_ws, size_t ws_size,
                              hipStream_t stream) {
    const float* x     = (const float*)d_in[0];
    const float* w_off = (const float*)d_in[1];
    const float* b_off = (const float*)d_in[2];
    const float* w     = (const float*)d_in[3];
    const float* bias  = (const float*)d_in[4];
    float* out = (float*)d_out;

    unsigned short* wbf  = (unsigned short*)d_ws;                   // 72 KB (tap-major)
    unsigned short* wobf = wbf + O_ * KTOT;                         // 36 KB (tap-major)
    unsigned short* xt   = wobf + 32 * KTOT;                        // 16.78 MB chunk-major

    const int wblocks = (96 * KTOT + 255) / 256;                    // 216
    prep_kernel <<<B_ * H_ + wblocks, 256, 0, stream>>>(x, w, w_off, xt, wbf);
    fused_kernel<<<B_ * HO_, 256, 0, stream>>>(xt, wobf, b_off, wbf, bias, out);
}

// Round 10
// 144.472 us; speedup vs baseline: 1.0991x; 1.0991x over previous
//
#include <hip/hip_runtime.h>

// Problem constants (fixed by setup_inputs)
#define B_   8
#define C_   64
#define O_   64
#define H_   128
#define W_   128
#define HO_  128
#define WO_  128
#define K2_  9
#define MOFF 18          // 2*K*K offset channels
#define PLANE (H_*W_)    // 16384
#define KTOT 576         // C_*K2_

// Row-band geometry (R19): TWO output rows per block -> 6 input rows
// (r0-2 .. r0+3), cols -2..129 zero-padded. Two planes (kh = channel half),
// each [6][132] cells of 16B (8 bf16).
#define BROWS 6
#define BCOLS 132
#define PSTRIDE (BROWS*BCOLS*8)   // 6336 ushorts = 12,672 B per plane

typedef short bf16x8 __attribute__((ext_vector_type(8)));
typedef float f32x16 __attribute__((ext_vector_type(16)));
typedef float f32x2  __attribute__((ext_vector_type(2)));
typedef unsigned int u32x4 __attribute__((ext_vector_type(4)));

__device__ __forceinline__ unsigned short f2bf(float f) {
    // round-to-nearest-even fp32 -> bf16
    unsigned u = __float_as_uint(f);
    u += 0x7fff + ((u >> 16) & 1);
    return (unsigned short)(u >> 16);
}
__device__ __forceinline__ float bf2f(short v) {
    return __uint_as_float(((unsigned)(unsigned short)v) << 16);
}
// unpack u32 (2 bf16) -> 2 floats (1 inst each: shl / and)
__device__ __forceinline__ f32x2 unpk(unsigned w) {
    f32x2 r;
    r.x = __uint_as_float(w << 16);
    r.y = __uint_as_float(w & 0xffff0000u);
    return r;
}

// ---------------------------------------------------------------------------
// PREP (merged): blocks < 1024 do the NHWC transpose; blocks >= 1024 convert
// both weight tensors to bf16 TAP-MAJOR rows (R16 vectorized version).
// xt layout (chunk-major NHWC):
//   xt[((cc*B + b)*PLANE + y*W + px)*16 + cl] = bf16(x[((b*64+cc*16+cl)*H+y)*W+px])
// ---------------------------------------------------------------------------
__global__ __launch_bounds__(256) void prep_kernel(const float* __restrict__ x,
                                                   const float* __restrict__ w,
                                                   const float* __restrict__ w_off,
                                                   unsigned short* __restrict__ xt,
                                                   unsigned short* __restrict__ wbf) {
    __shared__ __align__(16) unsigned short T[64 * 132];  // stride 132: ushort4-aligned
    const int tid = threadIdx.x;
    if (blockIdx.x >= B_ * H_) {                // ---- weight conversion ----
        int i = (blockIdx.x - B_ * H_) * 256 + tid;   // 96*576 = 55296
        if (i < 96 * KTOT) {
            int o = i / KTOT, pos = i % KTOT;
            int cc = pos / 144, r = pos % 144, t = r / 16, cl = r % 16;
            int c = cc * 16 + cl;
            unsigned short v;
            if (o < O_)             v = f2bf(w[o * KTOT + c * 9 + t]);
            else if (o < O_ + MOFF) v = f2bf(w_off[(o - O_) * KTOT + c * 9 + t]);
            else                    v = 0;
            wbf[i] = v;
        }
        return;
    }
    // ---- NHWC transpose ----
    const int b = blockIdx.x & 7;
    const int y = blockIdx.x >> 3;
    const float4* src4 = (const float4*)(x + (size_t)b * C_ * PLANE + y * W_);
    for (int i = tid; i < 64 * 32; i += 256) {  // 2048 float4 cells, 8 iters
        int c = i >> 5, px4 = i & 31;
        float4 v = src4[c * (PLANE / 4) + px4];
        ushort4 t = { f2bf(v.x), f2bf(v.y), f2bf(v.z), f2bf(v.w) };
        *(ushort4*)&T[c * 132 + px4 * 4] = t;
    }
    __syncthreads();
    for (int j = tid; j < 128 * 4; j += 256) {
        int cc = j >> 7, px = j & 127;
        unsigned short* dst = xt + ((size_t)(cc * B_ + b) * PLANE + y * W_ + px) * 16;
        ushort4 v0 = { T[(cc*16+ 0)*132+px], T[(cc*16+ 1)*132+px],
                       T[(cc*16+ 2)*132+px], T[(cc*16+ 3)*132+px] };
        ushort4 v1 = { T[(cc*16+ 4)*132+px], T[(cc*16+ 5)*132+px],
                       T[(cc*16+ 6)*132+px], T[(cc*16+ 7)*132+px] };
        ushort4 v2 = { T[(cc*16+ 8)*132+px], T[(cc*16+ 9)*132+px],
                       T[(cc*16+10)*132+px], T[(cc*16+11)*132+px] };
        ushort4 v3 = { T[(cc*16+12)*132+px], T[(cc*16+13)*132+px],
                       T[(cc*16+14)*132+px], T[(cc*16+15)*132+px] };
        *(ushort4*)(dst)      = v0;
        *(ushort4*)(dst + 4)  = v1;
        *(ushort4*)(dst + 8)  = v2;
        *(ushort4*)(dst + 12) = v3;
    }
}

// ---------------------------------------------------------------------------
// FUSED offset-conv + deformable-conv (R19 = R15 with TWO ROWS PER BLOCK).
// R18 post-mortem: VGPR_Count=64 is ARCH-only; acc AGPRs sit on top in the
// unified file -> wave is at the 128-reg total cap at 4 waves/SIMD. All
// >64-arch-reg ILP schemes (R14/R17/R18) spilled. R16 null = global-load
// latency covered. Remaining addressable cost: per-ROW serial structure
// (8 staging rounds + 18 barriers per single output row).
// R19: block = (b, row-pair), 512 threads = 8 waves; waves 0-3 -> row r0,
// waves 4-7 -> row r0+1, sharing one band:
//   - phase B band = 6 rows for 2 outputs (was 5 for 1): -40% bytes/row
//   - phase A band = 4 rows for 2 outputs (was 3 for 1): -33% bytes/row
//   - staging rounds and barriers PER ROW halve
// Per-wave phase A/B code is byte-identical to R15 (same M/N tiles, same
// packed blend, same 64-arch-reg profile -> no allocator fight).
// LDS = 25,344(band) + 18,432(lo[18][256]) = 43,776 B. Regs cap residency at
// 2 blocks/CU (16 waves/CU, same as R15). Grid 512 = exactly 2/CU.
// Tripwire: WRITE_SIZE > ~33MB = spill = revert. Flat result (+-3us) =
// declare structural floor (pre-committed).
// ---------------------------------------------------------------------------
__global__ __launch_bounds__(512, 4) void fused_kernel(const unsigned short* __restrict__ xt,
        const unsigned short* __restrict__ wobf, const float* __restrict__ b_off,
        const unsigned short* __restrict__ wbf, const float* __restrict__ bias,
        float* __restrict__ out) {
    __shared__ __align__(16) unsigned short band[2 * PSTRIDE];   // 25,344 B
    __shared__ float lo[MOFF * 256];                             // 18,432 B
    const int tid  = threadIdx.x;
    const int id   = blockIdx.x;                // 512
    const int b    = id & 7;                    // batch-per-XCD heuristic
    const int r0   = (id >> 3) << 1;            // first output row of the pair
    const int wv   = tid >> 6;                  // wave 0..7
    const int rl   = wv >> 2;                   // row-local 0/1
    const int ho   = r0 + rl;                   // this wave's output row
    const int lane = tid & 63;
    const int m    = lane & 31;
    const int kh   = lane >> 5;                 // channel half
    const int pxg  = ((wv & 3) << 5) + m;       // owned output pixel (col)

    // Coalesced band staging: cell j=(r,c); thread loads 32B (16 ch) and
    // writes 16B to each plane. Consecutive threads read consecutive 32B.
    // ybase = input row of band row 0.
    auto stage = [&](const unsigned short* xtc, int ybase, int nrows) {
        const int npos = nrows * BCOLS;         // <= 792 < 2*512
        uint4 va[2], vb[2];
        #pragma unroll
        for (int it = 0; it < 2; ++it) {        // issue all loads first
            va[it] = (uint4){0, 0, 0, 0};
            vb[it] = (uint4){0, 0, 0, 0};
            int j = tid + it * 512;
            if (j < npos) {
                int r = j / BCOLS, c = j - r * BCOLS;
                int y = ybase + r, x = c - 2;
                if (((unsigned)y < (unsigned)H_) && ((unsigned)x < (unsigned)W_)) {
                    const uint4* gp = (const uint4*)(xtc + (y * W_ + x) * 16);
                    va[it] = gp[0];
                    vb[it] = gp[1];
                }
            }
        }
        #pragma unroll
        for (int it = 0; it < 2; ++it) {
            int j = tid + it * 512;
            if (j < npos) {
                int r = j / BCOLS, c = j - r * BCOLS;
                int s = (r * BCOLS + c) * 8;
                *(uint4*)&band[s]           = va[it];
                *(uint4*)&band[PSTRIDE + s] = vb[it];
            }
        }
    };

    // ================= Phase A: offset conv (per-wave M=32, N=32) ==========
    // Band rows 0..3 = input rows r0-1 .. r0+2. Tap band row = rl + ks/3.
    f32x16 acc0 = {};
    for (int cc = 0; cc < 4; ++cc) {
        const unsigned short* xtc = xt + (size_t)(cc * B_ + b) * PLANE * 16;
        stage(xtc, r0 - 1, 4);
        __syncthreads();                        // band ready
        #pragma unroll
        for (int ks = 0; ks < 9; ++ks) {
            bf16x8 a = *(const bf16x8*)&wobf[m * KTOT + cc * 144 + ks * 16 + kh * 8];
            bf16x8 s = *(const bf16x8*)&band[kh * PSTRIDE +
                        ((rl + ks / 3) * BCOLS + pxg + ks % 3 + 1) * 8];
            acc0 = __builtin_amdgcn_mfma_f32_32x32x16_bf16(a, s, acc0, 0, 0, 0);
        }
        __syncthreads();                        // reads done before restage
    }
    // offsets -> lo[mo][rl*128 + px] (D col = pixel = lane m -> own px tile)
    #pragma unroll
    for (int r = 0; r < 16; ++r) {
        int mo = (r & 3) + ((r >> 2) << 3) + (kh << 2);
        if (mo < MOFF) lo[mo * 256 + rl * 128 + pxg] = acc0[r] + b_off[mo];
    }
    __syncthreads();                            // lo ready

    // ================= Phase B: deformable conv (per-wave M=64, N=32) ======
    // Band rows 0..5 = input rows r0-2 .. r0+3. rb_ = y0 - (r0-2), fast path
    // needs corners rb_, rb_+1 in 0..5 -> oob iff (unsigned)rb_ > 4.
    f32x16 acc[2] = {};
    for (int cc = 0; cc < 4; ++cc) {
        const unsigned short* xtc = xt + (size_t)(cc * B_ + b) * PLANE * 16;
        stage(xtc, r0 - 2, 6);
        __syncthreads();                        // band ready
        #pragma unroll
        for (int ks = 0; ks < 9; ++ks) {
            // per-tap coords recomputed per cc (R15: no live array spanning
            // the staging burst -> no spill)
            float py  = (float)(ho - 1 + ks / 3) + lo[(2 * ks) * 256 + rl * 128 + pxg];
            float pxc = (float)(pxg - 1 + ks % 3) + lo[(2 * ks + 1) * 256 + rl * 128 + pxg];
            float fy = floorf(py), fx = floorf(pxc);
            float wy = py - fy,    wx = pxc - fx;
            int y0 = (int)fy, x0 = (int)fx;
            int rb_ = y0 - r0 + 2, cb = x0 + 2;
            bool oob = ((unsigned)rb_ > 4u) || ((unsigned)cb > 130u);
            int rbc = min(max(rb_, 0), 4), cbc = min(max(cb, 0), 130);
            const unsigned short* bp = &band[kh * PSTRIDE + (rbc * BCOLS + cbc) * 8];
            const uint4 c00 = *(const uint4*)bp;
            const uint4 c01 = *(const uint4*)(bp + 8);
            const uint4 c10 = *(const uint4*)(bp + BCOLS * 8);
            const uint4 c11 = *(const uint4*)(bp + BCOLS * 8 + 8);
            const f32x2 wx2 = { wx, wx };
            const f32x2 wy2 = { wy, wy };
            u32x4 vr;
            #pragma unroll
            for (int pq = 0; pq < 4; ++pq) {
                unsigned w00 = (pq==0)?c00.x:(pq==1)?c00.y:(pq==2)?c00.z:c00.w;
                unsigned w01 = (pq==0)?c01.x:(pq==1)?c01.y:(pq==2)?c01.z:c01.w;
                unsigned w10 = (pq==0)?c10.x:(pq==1)?c10.y:(pq==2)?c10.z:c10.w;
                unsigned w11 = (pq==0)?c11.x:(pq==1)?c11.y:(pq==2)?c11.z:c11.w;
                f32x2 a2 = unpk(w00), b2 = unpk(w01);
                f32x2 c2 = unpk(w10), d2 = unpk(w11);
                f32x2 top = a2 + wx2 * (b2 - a2);     // v_pk ops on CDNA
                f32x2 bot = c2 + wx2 * (d2 - c2);
                f32x2 r2  = top + wy2 * (bot - top);
                unsigned pk;
                asm("v_cvt_pk_bf16_f32 %0, %1, %2" : "=v"(pk) : "v"(r2.x), "v"(r2.y));
                vr[pq] = pk;
            }
            bf16x8 v = __builtin_bit_cast(bf16x8, vr);
            // rare slow path: offsets outside the band -> exact global gather
            if (__builtin_expect(__any(oob), 0)) {
                if (oob) {
                    float s8[8];
                    #pragma unroll
                    for (int j = 0; j < 8; ++j) s8[j] = 0.f;
                    #pragma unroll
                    for (int c2i = 0; c2i < 4; ++c2i) {
                        int yy = y0 + (c2i >> 1);
                        int xx = x0 + (c2i & 1);
                        bool valid = ((unsigned)yy < (unsigned)H_) && ((unsigned)xx < (unsigned)W_);
                        int yc = min(max(yy, 0), H_ - 1);
                        int xc = min(max(xx, 0), W_ - 1);
                        float wgt = ((c2i >> 1) ? wy : 1.f - wy) * ((c2i & 1) ? wx : 1.f - wx);
                        wgt = valid ? wgt : 0.f;
                        const unsigned short* rp = xtc + (yc * W_ + xc) * 16 + kh * 8;
                        bf16x8 u = *(const bf16x8*)rp;
                        #pragma unroll
                        for (int j = 0; j < 8; ++j) s8[j] += wgt * bf2f(u[j]);
                    }
                    #pragma unroll
                    for (int j = 0; j < 8; ++j) v[j] = (short)f2bf(s8[j]);
                }
            }
            // MFMA: M=64 via two A-rows; A-fragments lazy (L2-hot wbf)
            bf16x8 a0 = *(const bf16x8*)&wbf[m * KTOT + cc * 144 + ks * 16 + kh * 8];
            bf16x8 a1 = *(const bf16x8*)&wbf[(32 + m) * KTOT + cc * 144 + ks * 16 + kh * 8];
            acc[0] = __builtin_amdgcn_mfma_f32_32x32x16_bf16(a0, v, acc[0], 0, 0, 0);
            acc[1] = __builtin_amdgcn_mfma_f32_32x32x16_bf16(a1, v, acc[1], 0, 0, 0);
        }
        __syncthreads();                        // reads done before restage
    }

    // epilogue: D col = pixel (pxg), row = out channel (+32 for acc[1])
    {
        float* op = out + (size_t)b * O_ * PLANE + ho * WO_ + pxg;
        #pragma unroll
        for (int nt = 0; nt < 2; ++nt) {
            #pragma unroll
            for (int r = 0; r < 16; ++r) {
                int mo = (nt << 5) + (r & 3) + ((r >> 2) << 3) + (kh << 2);
                __builtin_nontemporal_store(acc[nt][r] + bias[mo], op + (size_t)mo * PLANE);
            }
        }
    }
}

// ---------------------------------------------------------------------------
extern "C" void kernel_launch(void* const* d_in, const int* in_sizes, int n_in,
                              void* d_out, int out_size, void* d_ws, size_t ws_size,
                              hipStream_t stream) {
    const float* x     = (const float*)d_in[0];
    const float* w_off = (const float*)d_in[1];
    const float* b_off = (const float*)d_in[2];
    const float* w     = (const float*)d_in[3];
    const float* bias  = (const float*)d_in[4];
    float* out = (float*)d_out;

    unsigned short* wbf  = (unsigned short*)d_ws;                   // 72 KB (tap-major)
    unsigned short* wobf = wbf + O_ * KTOT;                         // 36 KB (tap-major)
    unsigned short* xt   = wobf + 32 * KTOT;                        // 16.78 MB chunk-major

    const int wblocks = (96 * KTOT + 255) / 256;                    // 216
    prep_kernel <<<B_ * H_ + wblocks, 256, 0, stream>>>(x, w, w_off, xt, wbf);
    fused_kernel<<<B_ * HO_ / 2, 512, 0, stream>>>(xt, wobf, b_off, wbf, bias, out);
}